// Round 3
// baseline (820.070 us; speedup 1.0000x reference)
//
#include <hip/hip_runtime.h>

#define ENTITIES_N 100000
#define RELATIONS_N 1000
#define WIDTH (2 * ENTITIES_N + RELATIONS_N)   // 201000 floats per row, divisible by 4
#define QWIDTH (WIDTH / 4)                     // 50250 float4 per row

// Native vector type: __builtin_nontemporal_store rejects HIP's float4 class.
typedef float vfloat4 __attribute__((ext_vector_type(4)));

// Fused one-hot materialization: one thread per aligned float4 of the output.
// Row r has exactly three 1.0s at columns hID[r], E+rID[r], E+R+tID[r]
// (disjoint segments; segment boundaries are multiples of 4, so an aligned
// 4-wide window matches at most one target). Everything else is 0.
// Each 64B cache line is written exactly once, fully, by consecutive lanes
// -> exact 823 MB HBM write traffic, no fill-kernel 4x over-write.
__global__ __launch_bounds__(256) void onehot_rows(
        const int* __restrict__ hID,
        const int* __restrict__ rID,
        const int* __restrict__ tID,
        vfloat4* __restrict__ out) {
    const int q = blockIdx.x * blockDim.x + threadIdx.x;  // float4 index in row
    if (q >= QWIDTH) return;
    const int row = blockIdx.y;
    const int col = q * 4;

    // Block-uniform loads, L2-hot (3 x 4KB index arrays).
    const int h = hID[row];
    const int r = ENTITIES_N + rID[row];
    const int t = ENTITIES_N + RELATIONS_N + tID[row];

    vfloat4 v;
    v.x = (col     == h || col     == r || col     == t) ? 1.0f : 0.0f;
    v.y = (col + 1 == h || col + 1 == r || col + 1 == t) ? 1.0f : 0.0f;
    v.z = (col + 2 == h || col + 2 == r || col + 2 == t) ? 1.0f : 0.0f;
    v.w = (col + 3 == h || col + 3 == r || col + 3 == t) ? 1.0f : 0.0f;

    // Streaming store: output (823 MB) far exceeds L3 (256 MB); don't pollute.
    __builtin_nontemporal_store(v, &out[(long long)row * QWIDTH + q]);
}

extern "C" void kernel_launch(void* const* d_in, const int* in_sizes, int n_in,
                              void* d_out, int out_size, void* d_ws, size_t ws_size,
                              hipStream_t stream) {
    // Inputs (setup_inputs order): z [B,128] f32 (unused), hID [B] i32, rID [B] i32, tID [B] i32
    const int* hID = (const int*)d_in[1];
    const int* rID = (const int*)d_in[2];
    const int* tID = (const int*)d_in[3];
    vfloat4* out = (vfloat4*)d_out;

    const int batch = in_sizes[2];

    const int block = 256;
    dim3 grid((QWIDTH + block - 1) / block, batch);  // (197, 1024)
    onehot_rows<<<grid, block, 0, stream>>>(hID, rID, tID, out);
}

// Round 4
// 815.574 us; speedup vs baseline: 1.0055x; 1.0055x over previous
//
#include <hip/hip_runtime.h>

#define ENTITIES_N 100000
#define RELATIONS_N 1000
#define WIDTH (2 * ENTITIES_N + RELATIONS_N)   // 201000 floats per row, divisible by 4
#define QWIDTH (WIDTH / 4)                     // 50250 float4 per row
#define Q_PER_BLOCK 1024                       // 256 threads x 4 float4 each = 16 KB/block

typedef float vfloat4 __attribute__((ext_vector_type(4)));

// Fused one-hot materialization, 4 stores/thread, plain (cached) stores.
// Store j of a block writes a contiguous 1 KB span (lane i at 16B*i) -> every
// 64B line is produced whole by 4 consecutive lanes of one instruction.
// Row r has exactly three 1.0s at columns hID[r], E+rID[r], E+R+tID[r];
// segment boundaries are multiples of 4 so each aligned float4 window matches
// at most one target.
__global__ __launch_bounds__(256) void onehot_rows(
        const int* __restrict__ hID,
        const int* __restrict__ rID,
        const int* __restrict__ tID,
        vfloat4* __restrict__ out) {
    const int row = blockIdx.y;
    const int qBase = blockIdx.x * Q_PER_BLOCK + threadIdx.x;

    // Block-uniform index loads (12 KB total across all rows -> L2-hot).
    const int h = hID[row];
    const int r = ENTITIES_N + rID[row];
    const int t = ENTITIES_N + RELATIONS_N + tID[row];

    vfloat4* rowOut = out + (long long)row * QWIDTH;

#pragma unroll
    for (int sub = 0; sub < 4; ++sub) {
        const int q = qBase + sub * 256;
        if (q < QWIDTH) {
            const int col = q * 4;
            vfloat4 v;
            v.x = (col     == h || col     == r || col     == t) ? 1.0f : 0.0f;
            v.y = (col + 1 == h || col + 1 == r || col + 1 == t) ? 1.0f : 0.0f;
            v.z = (col + 2 == h || col + 2 == r || col + 2 == t) ? 1.0f : 0.0f;
            v.w = (col + 3 == h || col + 3 == r || col + 3 == t) ? 1.0f : 0.0f;
            rowOut[q] = v;
        }
    }
}

extern "C" void kernel_launch(void* const* d_in, const int* in_sizes, int n_in,
                              void* d_out, int out_size, void* d_ws, size_t ws_size,
                              hipStream_t stream) {
    // Inputs (setup_inputs order): z [B,128] f32 (unused), hID [B] i32, rID [B] i32, tID [B] i32
    const int* hID = (const int*)d_in[1];
    const int* rID = (const int*)d_in[2];
    const int* tID = (const int*)d_in[3];
    vfloat4* out = (vfloat4*)d_out;

    const int batch = in_sizes[2];

    dim3 grid((QWIDTH + Q_PER_BLOCK - 1) / Q_PER_BLOCK, batch);  // (50, 1024)
    onehot_rows<<<grid, 256, 0, stream>>>(hID, rID, tID, out);
}